// Round 5
// baseline (472.690 us; speedup 1.0000x reference)
//
#include <hip/hip_runtime.h>
#include <hip/hip_bf16.h>
#include <math.h>

// Problem constants
#define BB 8
#define SS 512
#define VV 32000
#define EE 256
#define NAx 12
#define NCc 24
#define NSt 576
#define MM (BB*SS)   // 4096

typedef __bf16 bf16x8 __attribute__((ext_vector_type(8)));
typedef float f32x4 __attribute__((ext_vector_type(4)));

#define MFMA16(a, b, c) __builtin_amdgcn_mfma_f32_16x16x32_bf16((a), (b), (c), 0, 0, 0)

__device__ __forceinline__ void gl2lds16(const void* g, void* l) {
  __builtin_amdgcn_global_load_lds(
      (const __attribute__((address_space(1))) void*)g,
      (__attribute__((address_space(3))) void*)l, 16, 0, 0);
}

#define FENCE() asm volatile("" ::: "memory")
#define BAR()   do { FENCE(); __builtin_amdgcn_s_barrier(); FENCE(); } while (0)

// ---------------- transpose f32 [R,C] -> bf16 [C,R], 64x64 tiles ----------
__global__ __launch_bounds__(256) void k_transpose64(
    const float* __restrict__ in, __hip_bfloat16* __restrict__ out, int R, int C)
{
  __shared__ float t[64][65];
  const int tx = threadIdx.x, ty = threadIdx.y;   // (64,4)
  const int c0 = blockIdx.x * 64, r0 = blockIdx.y * 64;
#pragma unroll
  for (int i = 0; i < 64; i += 4)
    t[ty + i][tx] = in[(size_t)(r0 + ty + i) * C + (c0 + tx)];
  __syncthreads();
#pragma unroll
  for (int i = 0; i < 64; i += 4)
    out[(size_t)(c0 + ty + i) * R + (r0 + tx)] = __float2bfloat16(t[tx][ty + i]);
}

// ---------------- embed -> axioms -> comps (f32) ----------------
__global__ __launch_bounds__(64) void k_embed_comps(
    const int* __restrict__ ids, const float* __restrict__ ET,
    const float* __restrict__ axw, const float* __restrict__ axb,
    const float* __restrict__ axg, const float* __restrict__ axbeta,
    const float* __restrict__ cw,  const float* __restrict__ cb,
    const float* __restrict__ cg,  const float* __restrict__ cbeta,
    float* __restrict__ comps)
{
  __shared__ float sw[EE * NAx];
  __shared__ float scw[NAx * NCc];
  const int tid = threadIdx.x;
  for (int i = tid; i < EE * NAx; i += 64) sw[i] = axw[i];
  for (int i = tid; i < NAx * NCc; i += 64) scw[i] = cw[i];
  __syncthreads();

  const int m = blockIdx.x * 64 + tid;
  const int id = ids[m];
  const float4* e4 = reinterpret_cast<const float4*>(ET + (size_t)id * EE);

  float a[NAx];
#pragma unroll
  for (int t = 0; t < NAx; ++t) a[t] = axb[t];

  for (int q = 0; q < EE / 4; ++q) {
    float4 v = e4[q];
#pragma unroll
    for (int c = 0; c < 4; ++c) {
      float x = (c == 0) ? v.x : (c == 1) ? v.y : (c == 2) ? v.z : v.w;
      const float* wrow = &sw[(q * 4 + c) * NAx];
#pragma unroll
      for (int t = 0; t < NAx; ++t) a[t] += x * wrow[t];
    }
  }
  {
    float mean = 0.f;
#pragma unroll
    for (int t = 0; t < NAx; ++t) mean += a[t];
    mean *= (1.0f / NAx);
    float var = 0.f;
#pragma unroll
    for (int t = 0; t < NAx; ++t) { float d = a[t] - mean; var += d * d; }
    var *= (1.0f / NAx);
    float rs = rsqrtf(var + 1e-5f);
#pragma unroll
    for (int t = 0; t < NAx; ++t)
      a[t] = tanhf((a[t] - mean) * rs * axg[t] + axbeta[t]);
  }
  float c24[NCc];
#pragma unroll
  for (int j = 0; j < NCc; ++j) c24[j] = cb[j];
#pragma unroll
  for (int t = 0; t < NAx; ++t) {
    float x = a[t];
    const float* wrow = &scw[t * NCc];
#pragma unroll
    for (int j = 0; j < NCc; ++j) c24[j] += x * wrow[j];
  }
  {
    float mean = 0.f;
#pragma unroll
    for (int j = 0; j < NCc; ++j) mean += c24[j];
    mean *= (1.0f / NCc);
    float var = 0.f;
#pragma unroll
    for (int j = 0; j < NCc; ++j) { float d = c24[j] - mean; var += d * d; }
    var *= (1.0f / NCc);
    float rs = rsqrtf(var + 1e-5f);
#pragma unroll
    for (int j = 0; j < NCc; ++j)
      c24[j] = tanhf((c24[j] - mean) * rs * cg[j] + cbeta[j]);
  }
#pragma unroll
  for (int j = 0; j < NCc; ++j) comps[(size_t)m * NCc + j] = c24[j];
}

// ---------------- state recurrence ----------------
__global__ __launch_bounds__(576) void k_recurrence(
    const float* __restrict__ comps, const float* __restrict__ mix,
    __hip_bfloat16* __restrict__ ST, float* __restrict__ fstate)
{
  __shared__ float sc[SS * NCc];
  const int b = blockIdx.x, tid = threadIdx.x;
  const float* src = comps + (size_t)b * SS * NCc;
  for (int i = tid; i < SS * NCc; i += 576) sc[i] = src[i];
  __syncthreads();

  const float sm = 1.0f / (1.0f + expf(-mix[0]));
  const int i = tid / NCc, j = tid - i * NCc;
  float st = 0.0f;
  __hip_bfloat16* stp = ST + (size_t)b * SS * NSt + tid;
  for (int t = 0; t < SS; ++t) {
    float ci = sc[t * NCc + i], cj = sc[t * NCc + j];
    st = 0.9f * st + sm * ci * cj;
    stp[(size_t)t * NSt] = __float2bfloat16(st);
  }
  fstate[b * NSt + tid] = st;
}

// ---------------- 128^2 bf16 GEMM (m97 structure) for GEMM1 ----------------
__global__ __launch_bounds__(256) void k_gemm_bt_gelu(
    const __hip_bfloat16* __restrict__ A,   // [M,K]
    const __hip_bfloat16* __restrict__ Bt,  // [N,K]
    const float* __restrict__ bias,
    __hip_bfloat16* __restrict__ Cb,
    int M, int N, int K)
{
  __shared__ __align__(16) __hip_bfloat16 As[128 * 32];
  __shared__ __align__(16) __hip_bfloat16 Bs[128 * 32];
  const int tid  = threadIdx.x;
  const int lane = tid & 63;
  const int w    = tid >> 6;
  const int wr   = w >> 1, wc = w & 1;
  const int m0 = blockIdx.y * 128;
  const int n0 = blockIdx.x * 128;
  const int lr = lane & 15;
  const int kb = lane >> 4;

  f32x4 acc[4][4];
#pragma unroll
  for (int i = 0; i < 4; ++i)
#pragma unroll
    for (int j = 0; j < 4; ++j) acc[i][j] = (f32x4){0.f, 0.f, 0.f, 0.f};

  for (int k0 = 0; k0 < K; k0 += 32) {
    __syncthreads();
#pragma unroll
    for (int p = 0; p < 2; ++p) {
      const int lbase = w * 2048 + p * 1024;
      const int o  = lbase + lane * 16;
      const int r  = o >> 6;
      const int sg = (o >> 4) & 3;
      gl2lds16(A  + (size_t)(m0 + r) * K + k0 + sg * 8, (char*)As + lbase);
      gl2lds16(Bt + (size_t)(n0 + r) * K + k0 + sg * 8, (char*)Bs + lbase);
    }
    asm volatile("s_waitcnt vmcnt(0)" ::: "memory");
    __syncthreads();

    bf16x8 af[4], bv[4];
#pragma unroll
    for (int mr = 0; mr < 4; ++mr)
      af[mr] = *reinterpret_cast<const bf16x8*>(&As[(wr * 64 + mr * 16 + lr) * 32 + kb * 8]);
#pragma unroll
    for (int nr = 0; nr < 4; ++nr)
      bv[nr] = *reinterpret_cast<const bf16x8*>(&Bs[(wc * 64 + nr * 16 + lr) * 32 + kb * 8]);
#pragma unroll
    for (int mr = 0; mr < 4; ++mr)
#pragma unroll
      for (int nr = 0; nr < 4; ++nr)
        acc[mr][nr] = MFMA16(af[mr], bv[nr], acc[mr][nr]);
  }

#pragma unroll
  for (int nr = 0; nr < 4; ++nr) {
    const int col = n0 + wc * 64 + nr * 16 + lr;
    const float bvs = bias[col];
#pragma unroll
    for (int mr = 0; mr < 4; ++mr) {
      const int rbase = m0 + wr * 64 + mr * 16 + kb * 4;
#pragma unroll
      for (int r = 0; r < 4; ++r) {
        float v = acc[mr][nr][r] + bvs;
        v = 0.5f * v * (1.0f + erff(v * 0.70710678118654752f));
        Cb[(size_t)(rbase + r) * N + col] = __float2bfloat16(v);
      }
    }
  }
}

// ---------------- 256^2 8-phase bf16 GEMM (T1..T5) for GEMM2 ----------------
// C[m][n] = sum_k A[m][k]*Bt[n][k] + bias[n], f32 out.
// Epilogue: LDS-transposed, 1KB-contiguous NT f32x4 stores.
// Requires: M%256==0, N%256==0, K%64==0, K/64>=2, grid%8==0.
__global__ __launch_bounds__(512, 1) void k_gemm2_8ph(
    const __hip_bfloat16* __restrict__ A,   // [M,K]
    const __hip_bfloat16* __restrict__ Bt,  // [N,K]
    const float* __restrict__ bias,
    float* __restrict__ C,
    int M, int N, int K, int tiles_m)
{
  __shared__ __align__(16) char smem[131072];  // A: 2x32KB @0, B: 2x32KB @65536

  const int NK  = K >> 6;
  const int tid = threadIdx.x;
  const int lane = tid & 63;
  const int w  = tid >> 6;          // 0..7
  const int wr = w >> 2;            // 0..1  (M half)
  const int wc = w & 3;             // 0..3  (N quarter)
  const int lr = lane & 15;
  const int kb = lane >> 4;

  // T1: bijective XCD swizzle (grid % 8 == 0)
  const int nwg = gridDim.x;
  const int cpx = nwg >> 3;
  const int s   = ((int)blockIdx.x & 7) * cpx + ((int)blockIdx.x >> 3);
  const int nt  = s / tiles_m;
  const int mt  = s - nt * tiles_m;
  const int m0  = mt << 8;
  const int n0  = nt << 8;

  // stage-side (linear LDS dest, inverse-swizzled global source)
  const int srow = tid >> 3;
  const int scol = ((tid & 7) ^ (srow & 7)) << 3;
  // read-side swizzle
  const int swz0 = (kb ^ (lr & 7)) << 4;
  const int swz1 = swz0 ^ 64;

#define STAGE_A(buf, H, tk0)                                                      \
  do {                                                                            \
    gl2lds16(A + (size_t)(m0 + (H)*128 + srow) * K + (tk0) + scol,                \
             smem + (buf)*32768 + (H)*16384 + w*1024);                            \
    gl2lds16(A + (size_t)(m0 + (H)*128 + 64 + srow) * K + (tk0) + scol,           \
             smem + (buf)*32768 + (H)*16384 + 8192 + w*1024);                     \
  } while (0)

#define STAGE_B(buf, H, tk0)                                                      \
  do {                                                                            \
    gl2lds16(Bt + (size_t)(n0 + (H)*128 + srow) * K + (tk0) + scol,               \
             smem + 65536 + (buf)*32768 + (H)*16384 + w*1024);                    \
    gl2lds16(Bt + (size_t)(n0 + (H)*128 + 64 + srow) * K + (tk0) + scol,          \
             smem + 65536 + (buf)*32768 + (H)*16384 + 8192 + w*1024);             \
  } while (0)

#define LDA(buf, mf, kh) \
  (*(const bf16x8*)(smem + (buf)*32768 + (wr*128 + (mf)*16 + lr)*128 + ((kh) ? swz1 : swz0)))
#define LDB(buf, nf, kh) \
  (*(const bf16x8*)(smem + 65536 + (buf)*32768 + (wc*64 + (nf)*16 + lr)*128 + ((kh) ? swz1 : swz0)))

  f32x4 acc[8][4];
#pragma unroll
  for (int i = 0; i < 8; ++i)
#pragma unroll
    for (int j = 0; j < 4; ++j) acc[i][j] = (f32x4){0.f, 0.f, 0.f, 0.f};

  float bvs[4];
#pragma unroll
  for (int nf = 0; nf < 4; ++nf) bvs[nf] = bias[n0 + wc * 64 + nf * 16 + lr];

  // ---- prologue: tile0 (A+B) and tile1 (A)
  STAGE_A(0, 0, 0);  STAGE_A(0, 1, 0);
  STAGE_B(0, 0, 0);  STAGE_B(0, 1, 0);
  STAGE_A(1, 0, 64); STAGE_A(1, 1, 64);
  asm volatile("s_waitcnt vmcnt(4)" ::: "memory");
  BAR();

#pragma unroll 1
  for (int t = 0; t < NK; ++t) {
    const int c  = t & 1;
    const int k1 = (t + 1) << 6;
    const int k2 = (t + 2) << 6;
    bf16x8 a0[8], b0[4], a1[8], b1[4];

    // phase 0
#pragma unroll
    for (int mf = 0; mf < 8; ++mf) a0[mf] = LDA(c, mf, 0);
#pragma unroll
    for (int nf = 0; nf < 4; ++nf) b0[nf] = LDB(c, nf, 0);
    if (t < NK - 1) STAGE_B(c ^ 1, 0, k1);
    BAR();
    asm volatile("s_waitcnt lgkmcnt(0)" ::: "memory");
    __builtin_amdgcn_sched_barrier(0);
    __builtin_amdgcn_s_setprio(1);
#pragma unroll
    for (int mf = 0; mf < 8; ++mf) {
      acc[mf][0] = MFMA16(a0[mf], b0[0], acc[mf][0]);
      acc[mf][1] = MFMA16(a0[mf], b0[1], acc[mf][1]);
    }
    __builtin_amdgcn_s_setprio(0);
    BAR();

    // phase 1
#pragma unroll
    for (int mf = 0; mf < 8; ++mf) a1[mf] = LDA(c, mf, 1);
#pragma unroll
    for (int nf = 0; nf < 4; ++nf) b1[nf] = LDB(c, nf, 1);
    if (t < NK - 1) STAGE_B(c ^ 1, 1, k1);
    BAR();
    asm volatile("s_waitcnt lgkmcnt(0)" ::: "memory");
    __builtin_amdgcn_sched_barrier(0);
    __builtin_amdgcn_s_setprio(1);
#pragma unroll
    for (int mf = 0; mf < 8; ++mf) {
      acc[mf][2] = MFMA16(a0[mf], b0[2], acc[mf][2]);
      acc[mf][3] = MFMA16(a0[mf], b0[3], acc[mf][3]);
    }
    __builtin_amdgcn_s_setprio(0);
    BAR();

    // phase 2
    if (t < NK - 2) STAGE_A(c, 0, k2);
    BAR();
    __builtin_amdgcn_s_setprio(1);
#pragma unroll
    for (int mf = 0; mf < 8; ++mf) {
      acc[mf][0] = MFMA16(a1[mf], b1[0], acc[mf][0]);
      acc[mf][1] = MFMA16(a1[mf], b1[1], acc[mf][1]);
    }
    __builtin_amdgcn_s_setprio(0);
    BAR();

    // phase 3
    if (t < NK - 2) STAGE_A(c, 1, k2);
    BAR();
    __builtin_amdgcn_s_setprio(1);
#pragma unroll
    for (int mf = 0; mf < 8; ++mf) {
      acc[mf][2] = MFMA16(a1[mf], b1[2], acc[mf][2]);
      acc[mf][3] = MFMA16(a1[mf], b1[3], acc[mf][3]);
    }
    __builtin_amdgcn_s_setprio(0);
    if (t < NK - 2) {
      asm volatile("s_waitcnt vmcnt(4)" ::: "memory");
    } else if (t == NK - 2) {
      asm volatile("s_waitcnt vmcnt(0)" ::: "memory");
    }
    BAR();
  }

  // ---- epilogue: 2 phases through LDS, 1KB-contiguous NT f32x4 stores ----
  // phase p stages rows {m0+wr*128+64p..+64} as LDS rows 0..127 (16B XOR swz),
  // then waves sweep rows sequentially storing 1KB contiguous per instr.
  float* ls = (float*)smem;
#pragma unroll 1
  for (int p = 0; p < 2; ++p) {
    BAR();  // previous phase's reads consumed (lgkm waited before each store)
#pragma unroll
    for (int mq = 0; mq < 4; ++mq) {
      const int mf = 4 * p + mq;
      const int lrow0 = wr * 64 + mq * 16 + kb * 4;
#pragma unroll
      for (int nf = 0; nf < 4; ++nf) {
        const int col = wc * 64 + nf * 16 + lr;
#pragma unroll
        for (int r = 0; r < 4; ++r) {
          const int row = lrow0 + r;
          const int seg = (col >> 2) ^ (row & 7);
          ls[row * 256 + seg * 4 + (col & 3)] = acc[mf][nf][r] + bvs[nf];
        }
      }
    }
    asm volatile("s_waitcnt lgkmcnt(0)" ::: "memory");
    BAR();
#pragma unroll
    for (int pass = 0; pass < 16; ++pass) {
      const int lrow = pass * 8 + w;
      const int grow = m0 + ((lrow >= 64) ? 128 : 0) + 64 * p + (lrow & 63);
      const int seg  = lane ^ (lrow & 7);
      f32x4 v = *(const f32x4*)&ls[lrow * 256 + seg * 4];
      __builtin_nontemporal_store(v, (f32x4*)&C[(size_t)grow * N + n0 + lane * 4]);
    }
  }
#undef STAGE_A
#undef STAGE_B
#undef LDA
#undef LDB
}

// ---------------- launch ----------------
extern "C" void kernel_launch(void* const* d_in, const int* in_sizes, int n_in,
                              void* d_out, int out_size, void* d_ws, size_t ws_size,
                              hipStream_t stream) {
  const int*   ids  = (const int*)  d_in[0];
  const float* ET   = (const float*)d_in[1];
  const float* axw  = (const float*)d_in[2];
  const float* axb  = (const float*)d_in[3];
  const float* axg  = (const float*)d_in[4];
  const float* axbt = (const float*)d_in[5];
  const float* cw   = (const float*)d_in[6];
  const float* cb   = (const float*)d_in[7];
  const float* cg   = (const float*)d_in[8];
  const float* cbt  = (const float*)d_in[9];
  const float* mix  = (const float*)d_in[10];
  const float* w1   = (const float*)d_in[11];
  const float* b1   = (const float*)d_in[12];
  const float* w2   = (const float*)d_in[13];
  const float* b2   = (const float*)d_in[14];

  float* out = (float*)d_out;

  char* ws = (char*)d_ws;
  size_t o = 0;
  __hip_bfloat16* W2T   = (__hip_bfloat16*)(ws + o); o += (size_t)VV * 512 * 2;
  __hip_bfloat16* W1T   = (__hip_bfloat16*)(ws + o); o += (size_t)512 * NSt * 2;
  float*          comps = (float*)(ws + o);          o += (size_t)MM * NCc * 4;
  __hip_bfloat16* STb   = (__hip_bfloat16*)(ws + o); o += (size_t)MM * NSt * 2;
  __hip_bfloat16* H     = (__hip_bfloat16*)(ws + o); o += (size_t)MM * 512 * 2;

  // W2 [512,32000] -> W2T bf16 [32000,512]; W1 [576,512] -> W1T bf16 [512,576]
  k_transpose64<<<dim3(VV / 64, 512 / 64), dim3(64, 4), 0, stream>>>(w2, W2T, 512, VV);
  k_transpose64<<<dim3(512 / 64, NSt / 64), dim3(64, 4), 0, stream>>>(w1, W1T, NSt, 512);

  k_embed_comps<<<MM / 64, 64, 0, stream>>>(ids, ET, axw, axb, axg, axbt,
                                            cw, cb, cg, cbt, comps);

  k_recurrence<<<BB, NSt, 0, stream>>>(comps, mix, STb, out + (size_t)MM * VV);

  // GEMM1: H = gelu(ST @ W1 + b1)  (M=4096, N=512, K=576)
  k_gemm_bt_gelu<<<dim3(512 / 128, MM / 128), 256, 0, stream>>>(
      STb, W1T, b1, H, MM, 512, NSt);

  // GEMM2: logits = H @ W2 + b2  (M=4096, N=32000, K=512)
  k_gemm2_8ph<<<(VV / 256) * (MM / 256), 512, 0, stream>>>(
      H, W2T, b2, out, MM, VV, 512, MM / 256);
}

// Round 6
// 277.369 us; speedup vs baseline: 1.7042x; 1.7042x over previous
//
#include <hip/hip_runtime.h>
#include <hip/hip_bf16.h>
#include <math.h>

// Problem constants
#define BB 8
#define SS 512
#define VV 32000
#define EE 256
#define NAx 12
#define NCc 24
#define NSt 576
#define MM (BB*SS)   // 4096

typedef __bf16 bf16x8 __attribute__((ext_vector_type(8)));
typedef float f32x4 __attribute__((ext_vector_type(4)));

#define MFMA16(a, b, c) __builtin_amdgcn_mfma_f32_16x16x32_bf16((a), (b), (c), 0, 0, 0)

__device__ __forceinline__ void gl2lds16(const void* g, void* l) {
  __builtin_amdgcn_global_load_lds(
      (const __attribute__((address_space(1))) void*)g,
      (__attribute__((address_space(3))) void*)l, 16, 0, 0);
}

#define FENCE() asm volatile("" ::: "memory")
#define BAR()   do { FENCE(); __builtin_amdgcn_s_barrier(); FENCE(); } while (0)

// ---------------- transpose f32 [R,C] -> bf16 [C,R], 64x64 tiles ----------
__global__ __launch_bounds__(256) void k_transpose64(
    const float* __restrict__ in, __hip_bfloat16* __restrict__ out, int R, int C)
{
  __shared__ float t[64][65];
  const int tx = threadIdx.x, ty = threadIdx.y;   // (64,4)
  const int c0 = blockIdx.x * 64, r0 = blockIdx.y * 64;
#pragma unroll
  for (int i = 0; i < 64; i += 4)
    t[ty + i][tx] = in[(size_t)(r0 + ty + i) * C + (c0 + tx)];
  __syncthreads();
#pragma unroll
  for (int i = 0; i < 64; i += 4)
    out[(size_t)(c0 + ty + i) * R + (r0 + tx)] = __float2bfloat16(t[tx][ty + i]);
}

// ---------------- embed -> axioms -> comps (f32) ----------------
__global__ __launch_bounds__(64) void k_embed_comps(
    const int* __restrict__ ids, const float* __restrict__ ET,
    const float* __restrict__ axw, const float* __restrict__ axb,
    const float* __restrict__ axg, const float* __restrict__ axbeta,
    const float* __restrict__ cw,  const float* __restrict__ cb,
    const float* __restrict__ cg,  const float* __restrict__ cbeta,
    float* __restrict__ comps)
{
  __shared__ float sw[EE * NAx];
  __shared__ float scw[NAx * NCc];
  const int tid = threadIdx.x;
  for (int i = tid; i < EE * NAx; i += 64) sw[i] = axw[i];
  for (int i = tid; i < NAx * NCc; i += 64) scw[i] = cw[i];
  __syncthreads();

  const int m = blockIdx.x * 64 + tid;
  const int id = ids[m];
  const float4* e4 = reinterpret_cast<const float4*>(ET + (size_t)id * EE);

  float a[NAx];
#pragma unroll
  for (int t = 0; t < NAx; ++t) a[t] = axb[t];

  for (int q = 0; q < EE / 4; ++q) {
    float4 v = e4[q];
#pragma unroll
    for (int c = 0; c < 4; ++c) {
      float x = (c == 0) ? v.x : (c == 1) ? v.y : (c == 2) ? v.z : v.w;
      const float* wrow = &sw[(q * 4 + c) * NAx];
#pragma unroll
      for (int t = 0; t < NAx; ++t) a[t] += x * wrow[t];
    }
  }
  {
    float mean = 0.f;
#pragma unroll
    for (int t = 0; t < NAx; ++t) mean += a[t];
    mean *= (1.0f / NAx);
    float var = 0.f;
#pragma unroll
    for (int t = 0; t < NAx; ++t) { float d = a[t] - mean; var += d * d; }
    var *= (1.0f / NAx);
    float rs = rsqrtf(var + 1e-5f);
#pragma unroll
    for (int t = 0; t < NAx; ++t)
      a[t] = tanhf((a[t] - mean) * rs * axg[t] + axbeta[t]);
  }
  float c24[NCc];
#pragma unroll
  for (int j = 0; j < NCc; ++j) c24[j] = cb[j];
#pragma unroll
  for (int t = 0; t < NAx; ++t) {
    float x = a[t];
    const float* wrow = &scw[t * NCc];
#pragma unroll
    for (int j = 0; j < NCc; ++j) c24[j] += x * wrow[j];
  }
  {
    float mean = 0.f;
#pragma unroll
    for (int j = 0; j < NCc; ++j) mean += c24[j];
    mean *= (1.0f / NCc);
    float var = 0.f;
#pragma unroll
    for (int j = 0; j < NCc; ++j) { float d = c24[j] - mean; var += d * d; }
    var *= (1.0f / NCc);
    float rs = rsqrtf(var + 1e-5f);
#pragma unroll
    for (int j = 0; j < NCc; ++j)
      c24[j] = tanhf((c24[j] - mean) * rs * cg[j] + cbeta[j]);
  }
#pragma unroll
  for (int j = 0; j < NCc; ++j) comps[(size_t)m * NCc + j] = c24[j];
}

// ---------------- state recurrence ----------------
__global__ __launch_bounds__(576) void k_recurrence(
    const float* __restrict__ comps, const float* __restrict__ mix,
    __hip_bfloat16* __restrict__ ST, float* __restrict__ fstate)
{
  __shared__ float sc[SS * NCc];
  const int b = blockIdx.x, tid = threadIdx.x;
  const float* src = comps + (size_t)b * SS * NCc;
  for (int i = tid; i < SS * NCc; i += 576) sc[i] = src[i];
  __syncthreads();

  const float sm = 1.0f / (1.0f + expf(-mix[0]));
  const int i = tid / NCc, j = tid - i * NCc;
  float st = 0.0f;
  __hip_bfloat16* stp = ST + (size_t)b * SS * NSt + tid;
  for (int t = 0; t < SS; ++t) {
    float ci = sc[t * NCc + i], cj = sc[t * NCc + j];
    st = 0.9f * st + sm * ci * cj;
    stp[(size_t)t * NSt] = __float2bfloat16(st);
  }
  fstate[b * NSt + tid] = st;
}

// ---------------- 128^2 bf16 GEMM (m97 structure) for GEMM1 ----------------
__global__ __launch_bounds__(256) void k_gemm_bt_gelu(
    const __hip_bfloat16* __restrict__ A,   // [M,K]
    const __hip_bfloat16* __restrict__ Bt,  // [N,K]
    const float* __restrict__ bias,
    __hip_bfloat16* __restrict__ Cb,
    int M, int N, int K)
{
  __shared__ __align__(16) __hip_bfloat16 As[128 * 32];
  __shared__ __align__(16) __hip_bfloat16 Bs[128 * 32];
  const int tid  = threadIdx.x;
  const int lane = tid & 63;
  const int w    = tid >> 6;
  const int wr   = w >> 1, wc = w & 1;
  const int m0 = blockIdx.y * 128;
  const int n0 = blockIdx.x * 128;
  const int lr = lane & 15;
  const int kb = lane >> 4;

  f32x4 acc[4][4];
#pragma unroll
  for (int i = 0; i < 4; ++i)
#pragma unroll
    for (int j = 0; j < 4; ++j) acc[i][j] = (f32x4){0.f, 0.f, 0.f, 0.f};

  for (int k0 = 0; k0 < K; k0 += 32) {
    __syncthreads();
#pragma unroll
    for (int p = 0; p < 2; ++p) {
      const int lbase = w * 2048 + p * 1024;
      const int o  = lbase + lane * 16;
      const int r  = o >> 6;
      const int sg = (o >> 4) & 3;
      gl2lds16(A  + (size_t)(m0 + r) * K + k0 + sg * 8, (char*)As + lbase);
      gl2lds16(Bt + (size_t)(n0 + r) * K + k0 + sg * 8, (char*)Bs + lbase);
    }
    asm volatile("s_waitcnt vmcnt(0)" ::: "memory");
    __syncthreads();

    bf16x8 af[4], bv[4];
#pragma unroll
    for (int mr = 0; mr < 4; ++mr)
      af[mr] = *reinterpret_cast<const bf16x8*>(&As[(wr * 64 + mr * 16 + lr) * 32 + kb * 8]);
#pragma unroll
    for (int nr = 0; nr < 4; ++nr)
      bv[nr] = *reinterpret_cast<const bf16x8*>(&Bs[(wc * 64 + nr * 16 + lr) * 32 + kb * 8]);
#pragma unroll
    for (int mr = 0; mr < 4; ++mr)
#pragma unroll
      for (int nr = 0; nr < 4; ++nr)
        acc[mr][nr] = MFMA16(af[mr], bv[nr], acc[mr][nr]);
  }

#pragma unroll
  for (int nr = 0; nr < 4; ++nr) {
    const int col = n0 + wc * 64 + nr * 16 + lr;
    const float bvs = bias[col];
#pragma unroll
    for (int mr = 0; mr < 4; ++mr) {
      const int rbase = m0 + wr * 64 + mr * 16 + kb * 4;
#pragma unroll
      for (int r = 0; r < 4; ++r) {
        float v = acc[mr][nr][r] + bvs;
        v = 0.5f * v * (1.0f + erff(v * 0.70710678118654752f));
        Cb[(size_t)(rbase + r) * N + col] = __float2bfloat16(v);
      }
    }
  }
}

// ---------------- 256^2 8-phase bf16 GEMM (T1..T5) for GEMM2 ----------------
// C[m][n] = sum_k A[m][k]*Bt[n][k] + bias[n], f32 out.
// Epilogue: LDS-transposed, 1KB-contiguous NT f32x4 stores, STATIC indexing.
// Requires: M%256==0, N%256==0, K%64==0, K/64>=2, grid%8==0.
__global__ __launch_bounds__(512, 1) void k_gemm2_8ph(
    const __hip_bfloat16* __restrict__ A,   // [M,K]
    const __hip_bfloat16* __restrict__ Bt,  // [N,K]
    const float* __restrict__ bias,
    float* __restrict__ C,
    int M, int N, int K, int tiles_m)
{
  __shared__ __align__(16) char smem[131072];  // A: 2x32KB @0, B: 2x32KB @65536

  const int NK  = K >> 6;
  const int tid = threadIdx.x;
  const int lane = tid & 63;
  const int w  = tid >> 6;          // 0..7
  const int wr = w >> 2;            // 0..1  (M half)
  const int wc = w & 3;             // 0..3  (N quarter)
  const int lr = lane & 15;
  const int kb = lane >> 4;

  // T1: bijective XCD swizzle (grid % 8 == 0)
  const int nwg = gridDim.x;
  const int cpx = nwg >> 3;
  const int s   = ((int)blockIdx.x & 7) * cpx + ((int)blockIdx.x >> 3);
  const int nt  = s / tiles_m;
  const int mt  = s - nt * tiles_m;
  const int m0  = mt << 8;
  const int n0  = nt << 8;

  // stage-side (linear LDS dest, inverse-swizzled global source)
  const int srow = tid >> 3;
  const int scol = ((tid & 7) ^ (srow & 7)) << 3;
  // read-side swizzle
  const int swz0 = (kb ^ (lr & 7)) << 4;
  const int swz1 = swz0 ^ 64;

#define STAGE_A(buf, H, tk0)                                                      \
  do {                                                                            \
    gl2lds16(A + (size_t)(m0 + (H)*128 + srow) * K + (tk0) + scol,                \
             smem + (buf)*32768 + (H)*16384 + w*1024);                            \
    gl2lds16(A + (size_t)(m0 + (H)*128 + 64 + srow) * K + (tk0) + scol,           \
             smem + (buf)*32768 + (H)*16384 + 8192 + w*1024);                     \
  } while (0)

#define STAGE_B(buf, H, tk0)                                                      \
  do {                                                                            \
    gl2lds16(Bt + (size_t)(n0 + (H)*128 + srow) * K + (tk0) + scol,               \
             smem + 65536 + (buf)*32768 + (H)*16384 + w*1024);                    \
    gl2lds16(Bt + (size_t)(n0 + (H)*128 + 64 + srow) * K + (tk0) + scol,          \
             smem + 65536 + (buf)*32768 + (H)*16384 + 8192 + w*1024);             \
  } while (0)

#define LDA(buf, mf, kh) \
  (*(const bf16x8*)(smem + (buf)*32768 + (wr*128 + (mf)*16 + lr)*128 + ((kh) ? swz1 : swz0)))
#define LDB(buf, nf, kh) \
  (*(const bf16x8*)(smem + 65536 + (buf)*32768 + (wc*64 + (nf)*16 + lr)*128 + ((kh) ? swz1 : swz0)))

  f32x4 acc[8][4];
#pragma unroll
  for (int i = 0; i < 8; ++i)
#pragma unroll
    for (int j = 0; j < 4; ++j) acc[i][j] = (f32x4){0.f, 0.f, 0.f, 0.f};

  float bvs[4];
#pragma unroll
  for (int nf = 0; nf < 4; ++nf) bvs[nf] = bias[n0 + wc * 64 + nf * 16 + lr];

  // ---- prologue: tile0 (A+B) and tile1 (A)
  STAGE_A(0, 0, 0);  STAGE_A(0, 1, 0);
  STAGE_B(0, 0, 0);  STAGE_B(0, 1, 0);
  STAGE_A(1, 0, 64); STAGE_A(1, 1, 64);
  asm volatile("s_waitcnt vmcnt(4)" ::: "memory");
  BAR();

#pragma unroll 1
  for (int t = 0; t < NK; ++t) {
    const int c  = t & 1;
    const int k1 = (t + 1) << 6;
    const int k2 = (t + 2) << 6;
    bf16x8 a0[8], b0[4], a1[8], b1[4];

    // phase 0
#pragma unroll
    for (int mf = 0; mf < 8; ++mf) a0[mf] = LDA(c, mf, 0);
#pragma unroll
    for (int nf = 0; nf < 4; ++nf) b0[nf] = LDB(c, nf, 0);
    if (t < NK - 1) STAGE_B(c ^ 1, 0, k1);
    BAR();
    asm volatile("s_waitcnt lgkmcnt(0)" ::: "memory");
    __builtin_amdgcn_sched_barrier(0);
    __builtin_amdgcn_s_setprio(1);
#pragma unroll
    for (int mf = 0; mf < 8; ++mf) {
      acc[mf][0] = MFMA16(a0[mf], b0[0], acc[mf][0]);
      acc[mf][1] = MFMA16(a0[mf], b0[1], acc[mf][1]);
    }
    __builtin_amdgcn_s_setprio(0);
    BAR();

    // phase 1
#pragma unroll
    for (int mf = 0; mf < 8; ++mf) a1[mf] = LDA(c, mf, 1);
#pragma unroll
    for (int nf = 0; nf < 4; ++nf) b1[nf] = LDB(c, nf, 1);
    if (t < NK - 1) STAGE_B(c ^ 1, 1, k1);
    BAR();
    asm volatile("s_waitcnt lgkmcnt(0)" ::: "memory");
    __builtin_amdgcn_sched_barrier(0);
    __builtin_amdgcn_s_setprio(1);
#pragma unroll
    for (int mf = 0; mf < 8; ++mf) {
      acc[mf][2] = MFMA16(a0[mf], b0[2], acc[mf][2]);
      acc[mf][3] = MFMA16(a0[mf], b0[3], acc[mf][3]);
    }
    __builtin_amdgcn_s_setprio(0);
    BAR();

    // phase 2
    if (t < NK - 2) STAGE_A(c, 0, k2);
    BAR();
    __builtin_amdgcn_s_setprio(1);
#pragma unroll
    for (int mf = 0; mf < 8; ++mf) {
      acc[mf][0] = MFMA16(a1[mf], b1[0], acc[mf][0]);
      acc[mf][1] = MFMA16(a1[mf], b1[1], acc[mf][1]);
    }
    __builtin_amdgcn_s_setprio(0);
    BAR();

    // phase 3
    if (t < NK - 2) STAGE_A(c, 1, k2);
    BAR();
    __builtin_amdgcn_s_setprio(1);
#pragma unroll
    for (int mf = 0; mf < 8; ++mf) {
      acc[mf][2] = MFMA16(a1[mf], b1[2], acc[mf][2]);
      acc[mf][3] = MFMA16(a1[mf], b1[3], acc[mf][3]);
    }
    __builtin_amdgcn_s_setprio(0);
    if (t < NK - 2) {
      asm volatile("s_waitcnt vmcnt(4)" ::: "memory");
    } else if (t == NK - 2) {
      asm volatile("s_waitcnt vmcnt(0)" ::: "memory");
    }
    BAR();
  }

  // ---- epilogue: 2 phases through LDS, 1KB-contiguous NT f32x4 stores.
  // P is a LITERAL (rule #20: all acc indexing compile-time; no scratch).
  float* ls = (float*)smem;

#define EPI_PHASE(P)                                                              \
  do {                                                                            \
    BAR();                                                                        \
    _Pragma("unroll")                                                             \
    for (int mq = 0; mq < 4; ++mq) {                                              \
      const int lrow0 = wr * 64 + mq * 16 + kb * 4;                               \
      _Pragma("unroll")                                                           \
      for (int nf = 0; nf < 4; ++nf) {                                            \
        const int col = wc * 64 + nf * 16 + lr;                                   \
        _Pragma("unroll")                                                         \
        for (int r = 0; r < 4; ++r) {                                             \
          const int row = lrow0 + r;                                              \
          const int seg = (col >> 2) ^ (row & 7);                                 \
          ls[row * 256 + seg * 4 + (col & 3)] = acc[4 * (P) + mq][nf][r] + bvs[nf]; \
        }                                                                         \
      }                                                                           \
    }                                                                             \
    asm volatile("s_waitcnt lgkmcnt(0)" ::: "memory");                            \
    BAR();                                                                        \
    _Pragma("unroll")                                                             \
    for (int pass = 0; pass < 16; ++pass) {                                       \
      const int lrow = pass * 8 + w;                                              \
      const int grow = m0 + ((lrow >= 64) ? 128 : 0) + 64 * (P) + (lrow & 63);    \
      const int seg  = lane ^ (lrow & 7);                                         \
      f32x4 v = *(const f32x4*)&ls[lrow * 256 + seg * 4];                         \
      __builtin_nontemporal_store(v, (f32x4*)&C[(size_t)grow * N + n0 + lane * 4]); \
    }                                                                             \
  } while (0)

  EPI_PHASE(0);
  EPI_PHASE(1);

#undef EPI_PHASE
#undef STAGE_A
#undef STAGE_B
#undef LDA
#undef LDB
}

// ---------------- launch ----------------
extern "C" void kernel_launch(void* const* d_in, const int* in_sizes, int n_in,
                              void* d_out, int out_size, void* d_ws, size_t ws_size,
                              hipStream_t stream) {
  const int*   ids  = (const int*)  d_in[0];
  const float* ET   = (const float*)d_in[1];
  const float* axw  = (const float*)d_in[2];
  const float* axb  = (const float*)d_in[3];
  const float* axg  = (const float*)d_in[4];
  const float* axbt = (const float*)d_in[5];
  const float* cw   = (const float*)d_in[6];
  const float* cb   = (const float*)d_in[7];
  const float* cg   = (const float*)d_in[8];
  const float* cbt  = (const float*)d_in[9];
  const float* mix  = (const float*)d_in[10];
  const float* w1   = (const float*)d_in[11];
  const float* b1   = (const float*)d_in[12];
  const float* w2   = (const float*)d_in[13];
  const float* b2   = (const float*)d_in[14];

  float* out = (float*)d_out;

  char* ws = (char*)d_ws;
  size_t o = 0;
  __hip_bfloat16* W2T   = (__hip_bfloat16*)(ws + o); o += (size_t)VV * 512 * 2;
  __hip_bfloat16* W1T   = (__hip_bfloat16*)(ws + o); o += (size_t)512 * NSt * 2;
  float*          comps = (float*)(ws + o);          o += (size_t)MM * NCc * 4;
  __hip_bfloat16* STb   = (__hip_bfloat16*)(ws + o); o += (size_t)MM * NSt * 2;
  __hip_bfloat16* H     = (__hip_bfloat16*)(ws + o); o += (size_t)MM * 512 * 2;

  // W2 [512,32000] -> W2T bf16 [32000,512]; W1 [576,512] -> W1T bf16 [512,576]
  k_transpose64<<<dim3(VV / 64, 512 / 64), dim3(64, 4), 0, stream>>>(w2, W2T, 512, VV);
  k_transpose64<<<dim3(512 / 64, NSt / 64), dim3(64, 4), 0, stream>>>(w1, W1T, NSt, 512);

  k_embed_comps<<<MM / 64, 64, 0, stream>>>(ids, ET, axw, axb, axg, axbt,
                                            cw, cb, cg, cbt, comps);

  k_recurrence<<<BB, NSt, 0, stream>>>(comps, mix, STb, out + (size_t)MM * VV);

  // GEMM1: H = gelu(ST @ W1 + b1)  (M=4096, N=512, K=576)
  k_gemm_bt_gelu<<<dim3(512 / 128, MM / 128), 256, 0, stream>>>(
      STb, W1T, b1, H, MM, 512, NSt);

  // GEMM2: logits = H @ W2 + b2  (M=4096, N=32000, K=512)
  k_gemm2_8ph<<<(VV / 256) * (MM / 256), 512, 0, stream>>>(
      H, W2T, b2, out, MM, VV, 512, MM / 256);
}

// Round 7
// 273.351 us; speedup vs baseline: 1.7292x; 1.0147x over previous
//
#include <hip/hip_runtime.h>
#include <hip/hip_bf16.h>
#include <math.h>

// Problem constants
#define BB 8
#define SS 512
#define VV 32000
#define EE 256
#define NAx 12
#define NCc 24
#define NSt 576
#define MM (BB*SS)   // 4096

typedef __bf16 bf16x8 __attribute__((ext_vector_type(8)));
typedef float f32x4 __attribute__((ext_vector_type(4)));

#define MFMA16(a, b, c) __builtin_amdgcn_mfma_f32_16x16x32_bf16((a), (b), (c), 0, 0, 0)

__device__ __forceinline__ void gl2lds16(const void* g, void* l) {
  __builtin_amdgcn_global_load_lds(
      (const __attribute__((address_space(1))) void*)g,
      (__attribute__((address_space(3))) void*)l, 16, 0, 0);
}

#define FENCE() asm volatile("" ::: "memory")
#define BAR()   do { FENCE(); __builtin_amdgcn_s_barrier(); FENCE(); } while (0)

// ---------------- transpose f32 [R,C] -> bf16 [C,R], 64x64 tiles ----------
__global__ __launch_bounds__(256) void k_transpose64(
    const float* __restrict__ in, __hip_bfloat16* __restrict__ out, int R, int C)
{
  __shared__ float t[64][65];
  const int tx = threadIdx.x, ty = threadIdx.y;   // (64,4)
  const int c0 = blockIdx.x * 64, r0 = blockIdx.y * 64;
#pragma unroll
  for (int i = 0; i < 64; i += 4)
    t[ty + i][tx] = in[(size_t)(r0 + ty + i) * C + (c0 + tx)];
  __syncthreads();
#pragma unroll
  for (int i = 0; i < 64; i += 4)
    out[(size_t)(c0 + ty + i) * R + (r0 + tx)] = __float2bfloat16(t[tx][ty + i]);
}

// ---------------- embed -> axioms -> comps (f32) ----------------
__global__ __launch_bounds__(64) void k_embed_comps(
    const int* __restrict__ ids, const float* __restrict__ ET,
    const float* __restrict__ axw, const float* __restrict__ axb,
    const float* __restrict__ axg, const float* __restrict__ axbeta,
    const float* __restrict__ cw,  const float* __restrict__ cb,
    const float* __restrict__ cg,  const float* __restrict__ cbeta,
    float* __restrict__ comps)
{
  __shared__ float sw[EE * NAx];
  __shared__ float scw[NAx * NCc];
  const int tid = threadIdx.x;
  for (int i = tid; i < EE * NAx; i += 64) sw[i] = axw[i];
  for (int i = tid; i < NAx * NCc; i += 64) scw[i] = cw[i];
  __syncthreads();

  const int m = blockIdx.x * 64 + tid;
  const int id = ids[m];
  const float4* e4 = reinterpret_cast<const float4*>(ET + (size_t)id * EE);

  float a[NAx];
#pragma unroll
  for (int t = 0; t < NAx; ++t) a[t] = axb[t];

  for (int q = 0; q < EE / 4; ++q) {
    float4 v = e4[q];
#pragma unroll
    for (int c = 0; c < 4; ++c) {
      float x = (c == 0) ? v.x : (c == 1) ? v.y : (c == 2) ? v.z : v.w;
      const float* wrow = &sw[(q * 4 + c) * NAx];
#pragma unroll
      for (int t = 0; t < NAx; ++t) a[t] += x * wrow[t];
    }
  }
  {
    float mean = 0.f;
#pragma unroll
    for (int t = 0; t < NAx; ++t) mean += a[t];
    mean *= (1.0f / NAx);
    float var = 0.f;
#pragma unroll
    for (int t = 0; t < NAx; ++t) { float d = a[t] - mean; var += d * d; }
    var *= (1.0f / NAx);
    float rs = rsqrtf(var + 1e-5f);
#pragma unroll
    for (int t = 0; t < NAx; ++t)
      a[t] = tanhf((a[t] - mean) * rs * axg[t] + axbeta[t]);
  }
  float c24[NCc];
#pragma unroll
  for (int j = 0; j < NCc; ++j) c24[j] = cb[j];
#pragma unroll
  for (int t = 0; t < NAx; ++t) {
    float x = a[t];
    const float* wrow = &scw[t * NCc];
#pragma unroll
    for (int j = 0; j < NCc; ++j) c24[j] += x * wrow[j];
  }
  {
    float mean = 0.f;
#pragma unroll
    for (int j = 0; j < NCc; ++j) mean += c24[j];
    mean *= (1.0f / NCc);
    float var = 0.f;
#pragma unroll
    for (int j = 0; j < NCc; ++j) { float d = c24[j] - mean; var += d * d; }
    var *= (1.0f / NCc);
    float rs = rsqrtf(var + 1e-5f);
#pragma unroll
    for (int j = 0; j < NCc; ++j)
      c24[j] = tanhf((c24[j] - mean) * rs * cg[j] + cbeta[j]);
  }
#pragma unroll
  for (int j = 0; j < NCc; ++j) comps[(size_t)m * NCc + j] = c24[j];
}

// ---------------- state recurrence ----------------
__global__ __launch_bounds__(576) void k_recurrence(
    const float* __restrict__ comps, const float* __restrict__ mix,
    __hip_bfloat16* __restrict__ ST, float* __restrict__ fstate)
{
  __shared__ float sc[SS * NCc];
  const int b = blockIdx.x, tid = threadIdx.x;
  const float* src = comps + (size_t)b * SS * NCc;
  for (int i = tid; i < SS * NCc; i += 576) sc[i] = src[i];
  __syncthreads();

  const float sm = 1.0f / (1.0f + expf(-mix[0]));
  const int i = tid / NCc, j = tid - i * NCc;
  float st = 0.0f;
  __hip_bfloat16* stp = ST + (size_t)b * SS * NSt + tid;
  for (int t = 0; t < SS; ++t) {
    float ci = sc[t * NCc + i], cj = sc[t * NCc + j];
    st = 0.9f * st + sm * ci * cj;
    stp[(size_t)t * NSt] = __float2bfloat16(st);
  }
  fstate[b * NSt + tid] = st;
}

// ---------------- 128^2 bf16 GEMM (m97 structure) for GEMM1 ----------------
__global__ __launch_bounds__(256) void k_gemm_bt_gelu(
    const __hip_bfloat16* __restrict__ A,   // [M,K]
    const __hip_bfloat16* __restrict__ Bt,  // [N,K]
    const float* __restrict__ bias,
    __hip_bfloat16* __restrict__ Cb,
    int M, int N, int K)
{
  __shared__ __align__(16) __hip_bfloat16 As[128 * 32];
  __shared__ __align__(16) __hip_bfloat16 Bs[128 * 32];
  const int tid  = threadIdx.x;
  const int lane = tid & 63;
  const int w    = tid >> 6;
  const int wr   = w >> 1, wc = w & 1;
  const int m0 = blockIdx.y * 128;
  const int n0 = blockIdx.x * 128;
  const int lr = lane & 15;
  const int kb = lane >> 4;

  f32x4 acc[4][4];
#pragma unroll
  for (int i = 0; i < 4; ++i)
#pragma unroll
    for (int j = 0; j < 4; ++j) acc[i][j] = (f32x4){0.f, 0.f, 0.f, 0.f};

  for (int k0 = 0; k0 < K; k0 += 32) {
    __syncthreads();
#pragma unroll
    for (int p = 0; p < 2; ++p) {
      const int lbase = w * 2048 + p * 1024;
      const int o  = lbase + lane * 16;
      const int r  = o >> 6;
      const int sg = (o >> 4) & 3;
      gl2lds16(A  + (size_t)(m0 + r) * K + k0 + sg * 8, (char*)As + lbase);
      gl2lds16(Bt + (size_t)(n0 + r) * K + k0 + sg * 8, (char*)Bs + lbase);
    }
    asm volatile("s_waitcnt vmcnt(0)" ::: "memory");
    __syncthreads();

    bf16x8 af[4], bv[4];
#pragma unroll
    for (int mr = 0; mr < 4; ++mr)
      af[mr] = *reinterpret_cast<const bf16x8*>(&As[(wr * 64 + mr * 16 + lr) * 32 + kb * 8]);
#pragma unroll
    for (int nr = 0; nr < 4; ++nr)
      bv[nr] = *reinterpret_cast<const bf16x8*>(&Bs[(wc * 64 + nr * 16 + lr) * 32 + kb * 8]);
#pragma unroll
    for (int mr = 0; mr < 4; ++mr)
#pragma unroll
      for (int nr = 0; nr < 4; ++nr)
        acc[mr][nr] = MFMA16(af[mr], bv[nr], acc[mr][nr]);
  }

#pragma unroll
  for (int nr = 0; nr < 4; ++nr) {
    const int col = n0 + wc * 64 + nr * 16 + lr;
    const float bvs = bias[col];
#pragma unroll
    for (int mr = 0; mr < 4; ++mr) {
      const int rbase = m0 + wr * 64 + mr * 16 + kb * 4;
#pragma unroll
      for (int r = 0; r < 4; ++r) {
        float v = acc[mr][nr][r] + bvs;
        v = 0.5f * v * (1.0f + erff(v * 0.70710678118654752f));
        Cb[(size_t)(rbase + r) * N + col] = __float2bfloat16(v);
      }
    }
  }
}

// ---------------- GEMM2: 128^2 tile, BK=64, 4 waves, 2 blocks/CU ----------
// C[m][n] = sum_k A[m][k]*Bt[n][k] + bias[n], f32 out.
// Same counted-vmcnt 4-phase schedule as the proven 256^2 kernel, with A
// staged in ph0/1 (t+1) and B staged in ph2/3 (t+2, into freed buffer).
// Requires: M%128==0, N%128==0, K%64==0, K/64>=2, grid%8==0.
__global__ __launch_bounds__(256, 2) void k_gemm2_128(
    const __hip_bfloat16* __restrict__ A,   // [M,K]
    const __hip_bfloat16* __restrict__ Bt,  // [N,K]
    const float* __restrict__ bias,
    float* __restrict__ C,
    int M, int N, int K, int tiles_m)
{
  __shared__ __align__(16) char smem[65536];  // A: 2x16KB @0, B: 2x16KB @32768

  const int NK  = K >> 6;
  const int tid = threadIdx.x;
  const int lane = tid & 63;
  const int w  = tid >> 6;          // 0..3
  const int wr = w >> 1;            // M half
  const int wc = w & 1;             // N half
  const int lr = lane & 15;
  const int kb = lane >> 4;

  // T1: bijective XCD swizzle (grid % 8 == 0); mt fastest -> B panel L2-reuse
  const int nwg = gridDim.x;
  const int cpx = nwg >> 3;
  const int s   = ((int)blockIdx.x & 7) * cpx + ((int)blockIdx.x >> 3);
  const int nt  = s / tiles_m;
  const int mt  = s - nt * tiles_m;
  const int m0  = mt << 7;
  const int n0  = nt << 7;

  // stage-side (linear LDS dest, inverse-swizzled global source)
  const int srow = tid >> 3;                       // 0..31
  const int scol = ((tid & 7) ^ (srow & 7)) << 3;  // element offset in K-tile
  // read-side swizzle
  const int swz0 = (kb ^ (lr & 7)) << 4;
  const int swz1 = swz0 ^ 64;

  // one call stages a 32-row chunk (R in {0,32,64,96}) of a 128x64 bf16 tile
#define STAGE_A(buf, R, tk0)                                              \
  gl2lds16(A + (size_t)(m0 + (R) + srow) * K + (tk0) + scol,              \
           smem + (buf)*16384 + (R)*128 + w*1024)
#define STAGE_B(buf, R, tk0)                                              \
  gl2lds16(Bt + (size_t)(n0 + (R) + srow) * K + (tk0) + scol,             \
           smem + 32768 + (buf)*16384 + (R)*128 + w*1024)

#define LDA(buf, mf, kh) \
  (*(const bf16x8*)(smem + (buf)*16384 + (wr*64 + (mf)*16 + lr)*128 + ((kh) ? swz1 : swz0)))
#define LDB(buf, nf, kh) \
  (*(const bf16x8*)(smem + 32768 + (buf)*16384 + (wc*64 + (nf)*16 + lr)*128 + ((kh) ? swz1 : swz0)))

  f32x4 acc[4][4];
#pragma unroll
  for (int i = 0; i < 4; ++i)
#pragma unroll
    for (int j = 0; j < 4; ++j) acc[i][j] = (f32x4){0.f, 0.f, 0.f, 0.f};

  float bvs[4];
#pragma unroll
  for (int nf = 0; nf < 4; ++nf) bvs[nf] = bias[n0 + wc * 64 + nf * 16 + lr];

  // ---- prologue: A(0), B(0), B(1)  (12 loads/thread, wait oldest 8)
  STAGE_A(0, 0, 0);  STAGE_A(0, 32, 0);  STAGE_A(0, 64, 0);  STAGE_A(0, 96, 0);
  STAGE_B(0, 0, 0);  STAGE_B(0, 32, 0);  STAGE_B(0, 64, 0);  STAGE_B(0, 96, 0);
  STAGE_B(1, 0, 64); STAGE_B(1, 32, 64); STAGE_B(1, 64, 64); STAGE_B(1, 96, 64);
  asm volatile("s_waitcnt vmcnt(4)" ::: "memory");   // tile0 (A+B) landed
  BAR();

#pragma unroll 1
  for (int t = 0; t < NK; ++t) {
    const int c  = t & 1;
    const int k1 = (t + 1) << 6;
    const int k2 = (t + 2) << 6;
    bf16x8 a0[4], b0[4], a1[4], b1[4];

    // phase 0: read kh0 frags; stage A(t+1) half; MFMA kh0 x nf0,1
#pragma unroll
    for (int mf = 0; mf < 4; ++mf) a0[mf] = LDA(c, mf, 0);
#pragma unroll
    for (int nf = 0; nf < 4; ++nf) b0[nf] = LDB(c, nf, 0);
    if (t < NK - 1) { STAGE_A(c ^ 1, 0, k1); STAGE_A(c ^ 1, 32, k1); }
    BAR();
    asm volatile("s_waitcnt lgkmcnt(0)" ::: "memory");
    __builtin_amdgcn_sched_barrier(0);
    __builtin_amdgcn_s_setprio(1);
#pragma unroll
    for (int mf = 0; mf < 4; ++mf) {
      acc[mf][0] = MFMA16(a0[mf], b0[0], acc[mf][0]);
      acc[mf][1] = MFMA16(a0[mf], b0[1], acc[mf][1]);
    }
    __builtin_amdgcn_s_setprio(0);
    BAR();

    // phase 1: read kh1 frags; stage A(t+1) half; MFMA kh0 x nf2,3
#pragma unroll
    for (int mf = 0; mf < 4; ++mf) a1[mf] = LDA(c, mf, 1);
#pragma unroll
    for (int nf = 0; nf < 4; ++nf) b1[nf] = LDB(c, nf, 1);
    if (t < NK - 1) { STAGE_A(c ^ 1, 64, k1); STAGE_A(c ^ 1, 96, k1); }
    BAR();
    asm volatile("s_waitcnt lgkmcnt(0)" ::: "memory");   // buf c fully consumed
    __builtin_amdgcn_sched_barrier(0);
    __builtin_amdgcn_s_setprio(1);
#pragma unroll
    for (int mf = 0; mf < 4; ++mf) {
      acc[mf][2] = MFMA16(a0[mf], b0[2], acc[mf][2]);
      acc[mf][3] = MFMA16(a0[mf], b0[3], acc[mf][3]);
    }
    __builtin_amdgcn_s_setprio(0);
    BAR();

    // phase 2: stage B(t+2) into just-freed buf c; MFMA kh1 x nf0,1
    if (t < NK - 2) { STAGE_B(c, 0, k2); STAGE_B(c, 32, k2); }
    BAR();
    __builtin_amdgcn_s_setprio(1);
#pragma unroll
    for (int mf = 0; mf < 4; ++mf) {
      acc[mf][0] = MFMA16(a1[mf], b1[0], acc[mf][0]);
      acc[mf][1] = MFMA16(a1[mf], b1[1], acc[mf][1]);
    }
    __builtin_amdgcn_s_setprio(0);
    BAR();

    // phase 3: stage B(t+2); MFMA kh1 x nf2,3; boundary wait
    if (t < NK - 2) { STAGE_B(c, 64, k2); STAGE_B(c, 96, k2); }
    BAR();
    __builtin_amdgcn_s_setprio(1);
#pragma unroll
    for (int mf = 0; mf < 4; ++mf) {
      acc[mf][2] = MFMA16(a1[mf], b1[2], acc[mf][2]);
      acc[mf][3] = MFMA16(a1[mf], b1[3], acc[mf][3]);
    }
    __builtin_amdgcn_s_setprio(0);
    if (t < NK - 2) {
      asm volatile("s_waitcnt vmcnt(4)" ::: "memory");   // tile t+1 landed
    } else if (t == NK - 2) {
      asm volatile("s_waitcnt vmcnt(0)" ::: "memory");
    }
    BAR();
  }

  // ---- epilogue: one LDS phase (128x128 f32 = 64 KB), 512B-contig NT stores
  float* ls = (float*)smem;
#pragma unroll
  for (int mf = 0; mf < 4; ++mf) {
#pragma unroll
    for (int nf = 0; nf < 4; ++nf) {
      const int col = wc * 64 + nf * 16 + lr;
#pragma unroll
      for (int r = 0; r < 4; ++r) {
        const int row = wr * 64 + mf * 16 + kb * 4 + r;
        const int seg = (col >> 2) ^ (row & 7);
        ls[row * 128 + seg * 4 + (col & 3)] = acc[mf][nf][r] + bvs[nf];
      }
    }
  }
  asm volatile("s_waitcnt lgkmcnt(0)" ::: "memory");
  BAR();
#pragma unroll
  for (int pass = 0; pass < 16; ++pass) {
    const int lrow = pass * 8 + w * 2 + (lane >> 5);
    const int seg  = (lane & 31) ^ (lrow & 7);
    f32x4 v = *(const f32x4*)&ls[lrow * 128 + seg * 4];
    __builtin_nontemporal_store(v,
        (f32x4*)&C[(size_t)(m0 + lrow) * N + n0 + (lane & 31) * 4]);
  }
#undef STAGE_A
#undef STAGE_B
#undef LDA
#undef LDB
}

// ---------------- launch ----------------
extern "C" void kernel_launch(void* const* d_in, const int* in_sizes, int n_in,
                              void* d_out, int out_size, void* d_ws, size_t ws_size,
                              hipStream_t stream) {
  const int*   ids  = (const int*)  d_in[0];
  const float* ET   = (const float*)d_in[1];
  const float* axw  = (const float*)d_in[2];
  const float* axb  = (const float*)d_in[3];
  const float* axg  = (const float*)d_in[4];
  const float* axbt = (const float*)d_in[5];
  const float* cw   = (const float*)d_in[6];
  const float* cb   = (const float*)d_in[7];
  const float* cg   = (const float*)d_in[8];
  const float* cbt  = (const float*)d_in[9];
  const float* mix  = (const float*)d_in[10];
  const float* w1   = (const float*)d_in[11];
  const float* b1   = (const float*)d_in[12];
  const float* w2   = (const float*)d_in[13];
  const float* b2   = (const float*)d_in[14];

  float* out = (float*)d_out;

  char* ws = (char*)d_ws;
  size_t o = 0;
  __hip_bfloat16* W2T   = (__hip_bfloat16*)(ws + o); o += (size_t)VV * 512 * 2;
  __hip_bfloat16* W1T   = (__hip_bfloat16*)(ws + o); o += (size_t)512 * NSt * 2;
  float*          comps = (float*)(ws + o);          o += (size_t)MM * NCc * 4;
  __hip_bfloat16* STb   = (__hip_bfloat16*)(ws + o); o += (size_t)MM * NSt * 2;
  __hip_bfloat16* H     = (__hip_bfloat16*)(ws + o); o += (size_t)MM * 512 * 2;

  // W2 [512,32000] -> W2T bf16 [32000,512]; W1 [576,512] -> W1T bf16 [512,576]
  k_transpose64<<<dim3(VV / 64, 512 / 64), dim3(64, 4), 0, stream>>>(w2, W2T, 512, VV);
  k_transpose64<<<dim3(512 / 64, NSt / 64), dim3(64, 4), 0, stream>>>(w1, W1T, NSt, 512);

  k_embed_comps<<<MM / 64, 64, 0, stream>>>(ids, ET, axw, axb, axg, axbt,
                                            cw, cb, cg, cbt, comps);

  k_recurrence<<<BB, NSt, 0, stream>>>(comps, mix, STb, out + (size_t)MM * VV);

  // GEMM1: H = gelu(ST @ W1 + b1)  (M=4096, N=512, K=576)
  k_gemm_bt_gelu<<<dim3(512 / 128, MM / 128), 256, 0, stream>>>(
      STb, W1T, b1, H, MM, 512, NSt);

  // GEMM2: logits = H @ W2 + b2  (M=4096, N=32000, K=512), 128^2 2-blocks/CU
  k_gemm2_128<<<(VV / 128) * (MM / 128), 256, 0, stream>>>(
      H, W2T, b2, out, MM, VV, 512, MM / 128);
}